// Round 10
// baseline (291.895 us; speedup 1.0000x reference)
//
#include <hip/hip_runtime.h>
#include <hip/hip_bf16.h>
#include <hip/hip_fp16.h>
#include <math.h>

typedef _Float16 f16;
typedef __attribute__((ext_vector_type(8))) _Float16 f16x8;
typedef __attribute__((ext_vector_type(4))) float f32x4;

// ---------------- JAX threefry2x32 (partitionable) + normal ----------------

static __device__ __forceinline__ unsigned rotl32(unsigned x, int d) {
  return (x << d) | (x >> (32 - d));
}

// key = (0, 42)  == jax.random.key(42)
static __device__ __forceinline__ void threefry_0_42(unsigned& x0, unsigned& x1) {
  const unsigned ks0 = 0u, ks1 = 42u, ks2 = 0u ^ 42u ^ 0x1BD11BDAu;
  x0 += ks0; x1 += ks1;
#define TF_R(r) { x0 += x1; x1 = rotl32(x1, (r)); x1 ^= x0; }
  TF_R(13) TF_R(15) TF_R(26) TF_R(6)
  x0 += ks1; x1 += ks2 + 1u;
  TF_R(17) TF_R(29) TF_R(16) TF_R(24)
  x0 += ks2; x1 += ks0 + 2u;
  TF_R(13) TF_R(15) TF_R(26) TF_R(6)
  x0 += ks0; x1 += ks1 + 3u;
  TF_R(17) TF_R(29) TF_R(16) TF_R(24)
  x0 += ks1; x1 += ks2 + 4u;
  TF_R(13) TF_R(15) TF_R(26) TF_R(6)
  x0 += ks2; x1 += ks0 + 5u;
#undef TF_R
}

static __device__ __forceinline__ float erfinv_f(float u) {
  float w = -logf((1.0f - u) * (1.0f + u));
  float p;
  if (w < 5.0f) {
    w = w - 2.5f;
    p = 2.81022636e-08f;
    p = fmaf(p, w, 3.43273939e-07f);
    p = fmaf(p, w, -3.5233877e-06f);
    p = fmaf(p, w, -4.39150654e-06f);
    p = fmaf(p, w, 0.00021858087f);
    p = fmaf(p, w, -0.00125372503f);
    p = fmaf(p, w, -0.00417768164f);
    p = fmaf(p, w, 0.246640727f);
    p = fmaf(p, w, 1.50140941f);
  } else {
    w = sqrtf(w) - 3.0f;
    p = -0.000200214257f;
    p = fmaf(p, w, 0.000100950558f);
    p = fmaf(p, w, 0.00134934322f);
    p = fmaf(p, w, -0.00367342844f);
    p = fmaf(p, w, 0.00573950773f);
    p = fmaf(p, w, -0.0076224613f);
    p = fmaf(p, w, 0.00943887047f);
    p = fmaf(p, w, 1.00167406f);
    p = fmaf(p, w, 2.83297682f);
  }
  return p * u;
}

// jax_threefry_partitionable=True: bits(j) = xor(threefry2x32(key, (0, j)))
static __device__ __forceinline__ float jax_normal_at(unsigned j) {
  unsigned x0 = 0u, x1 = j;
  threefry_0_42(x0, x1);
  unsigned bits = x0 ^ x1;
  float f = __uint_as_float((bits >> 9) | 0x3f800000u) - 1.0f;   // [0,1)
  float u = fmaf(f, 1.99999994f, -0.99999994f);
  return 1.41421356237f * erfinv_f(u);
}

// ---------------- setup kernels ----------------

__global__ void zero_i_kernel(int* __restrict__ p, int n) {
  int i = blockIdx.x * blockDim.x + threadIdx.x;
  if (i < n) p[i] = 0;
}

__global__ void degree_i_kernel(const int* __restrict__ dstI, int* __restrict__ cnt, int ne) {
  int e = blockIdx.x * blockDim.x + threadIdx.x;
  if (e < ne) atomicAdd(&cnt[dstI[e]], 1);
}

// ---- exclusive scan of cnt[n] -> rowptr ----
__global__ __launch_bounds__(256) void scan1_kernel(const int* __restrict__ cnt,
                                                    int* __restrict__ rowptr,
                                                    int* __restrict__ bsum, int n) {
  __shared__ int s[256];
  const int t = threadIdx.x;
  const int base = blockIdx.x * 1024 + t * 4;
  int v0, v1, v2, v3;
  if (base + 3 < n) {
    int4 v = *(const int4*)(cnt + base);
    v0 = v.x; v1 = v.y; v2 = v.z; v3 = v.w;
  } else {
    v0 = (base + 0 < n) ? cnt[base + 0] : 0;
    v1 = (base + 1 < n) ? cnt[base + 1] : 0;
    v2 = (base + 2 < n) ? cnt[base + 2] : 0;
    v3 = (base + 3 < n) ? cnt[base + 3] : 0;
  }
  int tot = v0 + v1 + v2 + v3;
  s[t] = tot;
  __syncthreads();
  for (int off = 1; off < 256; off <<= 1) {
    int x = (t >= off) ? s[t - off] : 0;
    __syncthreads();
    s[t] += x;
    __syncthreads();
  }
  int excl = s[t] - tot;
  if (t == 255) bsum[blockIdx.x] = s[t];
  if (base + 0 < n) rowptr[base + 0] = excl;
  if (base + 1 < n) rowptr[base + 1] = excl + v0;
  if (base + 2 < n) rowptr[base + 2] = excl + v0 + v1;
  if (base + 3 < n) rowptr[base + 3] = excl + v0 + v1 + v2;
}

__global__ __launch_bounds__(256) void scanP_kernel(int* __restrict__ bsum,
                                                    int* __restrict__ boff,
                                                    int nb, int* __restrict__ rowptr,
                                                    int n, int ne) {
  __shared__ int s[256];
  const int t = threadIdx.x;
  int v = (t < nb) ? bsum[t] : 0;
  s[t] = v;
  __syncthreads();
  for (int off = 1; off < 256; off <<= 1) {
    int x = (t >= off) ? s[t - off] : 0;
    __syncthreads();
    s[t] += x;
    __syncthreads();
  }
  if (t < nb) boff[t] = s[t] - v;
  if (t == 0) rowptr[n] = ne;
}

// adds block offsets; computes dinv; inits bucket cursors bcur[b] = rowptr[b<<8]
__global__ void scan2_kernel(int* __restrict__ rowptr, const int* __restrict__ boff,
                             const int* __restrict__ cnt, float* __restrict__ dinv,
                             int* __restrict__ bcur, int n) {
  int i = blockIdx.x * blockDim.x + threadIdx.x;
  if (i < n) {
    int rp = rowptr[i] + boff[i >> 10];
    rowptr[i] = rp;
    if ((i & 255) == 0) bcur[i >> 8] = rp;
    float d = (float)cnt[i] + 1.0f;
    dinv[i] = 1.0f / sqrtf(d);
  }
}

// ---------------- two-pass binned fill ----------------
#define EPB 2048
__global__ __launch_bounds__(256) void fillA_kernel(
    const int* __restrict__ srcI, const int* __restrict__ dstI,
    int* __restrict__ bcur, unsigned* __restrict__ coarse, int ne) {
  __shared__ int hist[256], hpre[256], hcur[256], gbase[256];
  __shared__ unsigned st[EPB];
  const int tid = threadIdx.x;
  const int base = blockIdx.x * EPB;

  hist[tid] = 0; hcur[tid] = 0;
  __syncthreads();

  int s[8], d[8];
#pragma unroll
  for (int k = 0; k < 8; ++k) {
    int e = base + k * 256 + tid;
    if (e < ne) { s[k] = srcI[e]; d[k] = dstI[e]; }
    else        { s[k] = -1;      d[k] = 0; }
  }
#pragma unroll
  for (int k = 0; k < 8; ++k)
    if (s[k] >= 0) atomicAdd(&hist[d[k] >> 8], 1);
  __syncthreads();

  int hv = hist[tid];
  hpre[tid] = hv;
  __syncthreads();
  for (int off = 1; off < 256; off <<= 1) {
    int x = (tid >= off) ? hpre[tid - off] : 0;
    __syncthreads();
    hpre[tid] += x;
    __syncthreads();
  }

#pragma unroll
  for (int k = 0; k < 8; ++k) {
    if (s[k] >= 0) {
      int b = d[k] >> 8;
      int pos = (hpre[b] - hist[b]) + atomicAdd(&hcur[b], 1);
      st[pos] = ((unsigned)b << 24) | ((unsigned)(d[k] & 255) << 16) | (unsigned)s[k];
    }
  }
  if (hist[tid] > 0) gbase[tid] = atomicAdd(&bcur[tid], hist[tid]);
  __syncthreads();

  int cntE = ne - base; if (cntE > EPB) cntE = EPB;
  for (int i = tid; i < cntE; i += 256) {
    unsigned v = st[i];
    int b = v >> 24;
    int excl = hpre[b] - hist[b];
    coarse[gbase[b] + (i - excl)] = v & 0x00FFFFFFu;
  }
}

__global__ __launch_bounds__(256) void fillB_kernel(
    const unsigned* __restrict__ coarse, const int* __restrict__ rowptr,
    unsigned short* __restrict__ ssrc, int n, int ne) {
  __shared__ int rcur[256];
  const int b = blockIdx.x;
  const int r0 = b << 8;
  const int tid = threadIdx.x;
  if (r0 + tid < n) rcur[tid] = rowptr[r0 + tid];
  const int e0 = rowptr[r0];
  const int e1 = (r0 + 256 <= n) ? rowptr[r0 + 256] : ne;
  __syncthreads();
  for (int e = e0 + tid; e < e1; e += 256) {
    unsigned v = coarse[e];
    int r = (v >> 16) & 255;
    int pos = atomicAdd(&rcur[r], 1);
    ssrc[pos] = (unsigned short)(v & 0xFFFFu);
  }
}

// ---------------- MFMA GEMM: {YA,YB}[n][32] = fp16(concat(X1,X2)) @ fp16(W) * dinv ----------------
// 128 nodes/block, 4 waves; wave = 32 rows x 64 cols; split column-halves to two packed tables.
template<int IN1, int IN2, bool X1HALF, bool DUALW>
__global__ __launch_bounds__(256) void gemm_mfma_kernel(
    const void* __restrict__ X1v, const float* __restrict__ X2,
    const float* __restrict__ Wa, const float* __restrict__ Wb,
    const float* __restrict__ dinv, __half* __restrict__ YA, __half* __restrict__ YB, int n) {
  constexpr int IN = IN1 + IN2;
  constexpr int IP = IN + 8;
  __shared__ f16 xs[128 * IP];
  __shared__ f16 wt[64 * IP];  // W transposed: wt[col][k]

  const int tid = threadIdx.x;
  const int base = blockIdx.x * 128;

  for (int i = tid; i < IN * 64; i += 256) {
    int k = i >> 6, c = i & 63;
    float w;
    if (DUALW) w = (c < 32) ? Wa[k * 32 + c] : Wb[k * 32 + (c - 32)];
    else       w = Wa[i];
    wt[c * IP + k] = (f16)w;
  }
  if (X1HALF) {
    const __half* X1 = (const __half*)X1v;
    for (int idx = tid; idx < 128 * (IN1 / 8); idx += 256) {
      int node = idx / (IN1 / 8);
      int k8 = (idx % (IN1 / 8)) * 8;
      int g = base + node;
      f16x8 v = {};
      if (g < n) v = *(const f16x8*)(X1 + (size_t)g * IN1 + k8);
      *(f16x8*)&xs[node * IP + k8] = v;
    }
  } else {
    const float* X1 = (const float*)X1v;
    for (int idx = tid; idx < 128 * (IN1 / 4); idx += 256) {
      int node = idx / (IN1 / 4);
      int k4 = (idx % (IN1 / 4)) * 4;
      int g = base + node;
      float4 v = (g < n) ? *(const float4*)(X1 + (size_t)g * IN1 + k4)
                         : make_float4(0.f, 0.f, 0.f, 0.f);
      f16* p = &xs[node * IP + k4];
      p[0] = (f16)v.x; p[1] = (f16)v.y; p[2] = (f16)v.z; p[3] = (f16)v.w;
    }
  }
  if (IN2 > 0) {
    for (int idx = tid; idx < 128 * (IN2 / 4); idx += 256) {
      int node = idx / (IN2 / 4);
      int k4 = (idx % (IN2 / 4)) * 4;
      int g = base + node;
      float4 v = (g < n) ? *(const float4*)(X2 + (size_t)g * IN2 + k4)
                         : make_float4(0.f, 0.f, 0.f, 0.f);
      f16* p = &xs[node * IP + IN1 + k4];
      p[0] = (f16)v.x; p[1] = (f16)v.y; p[2] = (f16)v.z; p[3] = (f16)v.w;
    }
  }
  __syncthreads();

  const int wid  = tid >> 6;
  const int lane = tid & 63;
  const int l15  = lane & 15;
  const int lk8  = (lane >> 4) * 8;

  f32x4 acc[2][4] = {{{0.f,0.f,0.f,0.f}}};
  constexpr int KB = IN / 32;
#pragma unroll
  for (int kb = 0; kb < KB; ++kb) {
    const int k0 = kb * 32 + lk8;
    f16x8 a0 = *(const f16x8*)&xs[(wid * 32 +      l15) * IP + k0];
    f16x8 a1 = *(const f16x8*)&xs[(wid * 32 + 16 + l15) * IP + k0];
#pragma unroll
    for (int ct = 0; ct < 4; ++ct) {
      f16x8 b = *(const f16x8*)&wt[(ct * 16 + l15) * IP + k0];
      acc[0][ct] = __builtin_amdgcn_mfma_f32_16x16x32_f16(a0, b, acc[0][ct], 0, 0, 0);
      acc[1][ct] = __builtin_amdgcn_mfma_f32_16x16x32_f16(a1, b, acc[1][ct], 0, 0, 0);
    }
  }

#pragma unroll
  for (int rt = 0; rt < 2; ++rt) {
#pragma unroll
    for (int i = 0; i < 4; ++i) {
      int node = base + wid * 32 + rt * 16 + (lane >> 4) * 4 + i;
      if (node < n) {
        float dv = dinv[node];
        YA[(size_t)node * 32 +  0 + l15] = __float2half(acc[rt][0][i] * dv);
        YA[(size_t)node * 32 + 16 + l15] = __float2half(acc[rt][1][i] * dv);
        YB[(size_t)node * 32 +  0 + l15] = __float2half(acc[rt][2][i] * dv);
        YB[(size_t)node * 32 + 16 + l15] = __float2half(acc[rt][3][i] * dv);
      }
    }
  }
}

// ---------------- half-table CSR gather (table = [n][32] fp16, 3.2MB, L2-resident) ----------------
// wave = node; lane = p*16 + cl: p = edge parity (0..3), cl = col-pair (cols 2cl,2cl+1).
// One load instruction covers 4 edges x 64B rows. Butterfly (^16,^32) combines parities.
// MODE 0: relu -> h half (cols HALF*32..). MODE 1 HALF 0: mean -> dout[NZ..].
// MODE 1 HALF 1: logvar -> dout[2NZ..], reads mean, computes z -> dout[0..].
// MODE 2: +bias -> outbuf float cols HALF*32...
template<int MODE, int HALF>
__global__ __launch_bounds__(256) void gatherH_kernel(
    const int* __restrict__ rowptr, const unsigned short* __restrict__ ssrc,
    const __half* __restrict__ tbl, const float* __restrict__ dinv,
    const float* __restrict__ bias, float* __restrict__ dout,
    __half* __restrict__ hout, int n) {
  const int node = (blockIdx.x * 256 + threadIdx.x) >> 6;
  const int lane = threadIdx.x & 63;
  if (node >= n) return;
  const int p  = lane >> 4;
  const int cl = lane & 15;

  float2 a0, a1;
  a0.x = a0.y = a1.x = a1.y = 0.f;
  if (p == 0) {
    float2 f = __half22float2(((const __half2*)(tbl + (size_t)node * 32))[cl]);
    a0 = f;  // self loop
  }

  const int beg = rowptr[node];
  const int end = rowptr[node + 1];
  for (int cbase = beg; cbase < end; cbase += 64) {
    int m = end - cbase; if (m > 64) m = 64;
    unsigned sv = (lane < m) ? (unsigned)ssrc[cbase + lane] : 0u;
    const int body = m & ~7;
    for (int k = 0; k < body; k += 8) {
      unsigned s0 = __shfl(sv, k + p, 64);
      unsigned s1 = __shfl(sv, k + 4 + p, 64);
      float2 f0 = __half22float2(((const __half2*)(tbl + (size_t)s0 * 32))[cl]);
      float2 f1 = __half22float2(((const __half2*)(tbl + (size_t)s1 * 32))[cl]);
      a0.x += f0.x; a0.y += f0.y;
      a1.x += f1.x; a1.y += f1.y;
    }
    {
      int k = body;
      unsigned s0 = __shfl(sv, k + p, 64);
      unsigned s1 = __shfl(sv, (k + 4 + p) & 63, 64);
      if (k + p < m) {
        float2 f0 = __half22float2(((const __half2*)(tbl + (size_t)s0 * 32))[cl]);
        a0.x += f0.x; a0.y += f0.y;
      }
      if (k + 4 + p < m) {
        float2 f1 = __half22float2(((const __half2*)(tbl + (size_t)s1 * 32))[cl]);
        a1.x += f1.x; a1.y += f1.y;
      }
    }
  }
  float2 acc;
  acc.x = a0.x + a1.x;
  acc.y = a0.y + a1.y;
  acc.x += __shfl(acc.x, lane ^ 16, 64);
  acc.y += __shfl(acc.y, lane ^ 16, 64);
  acc.x += __shfl(acc.x, lane ^ 32, 64);
  acc.y += __shfl(acc.y, lane ^ 32, 64);
  const float dv = dinv[node];
  float vx = acc.x * dv + bias[2 * cl];
  float vy = acc.y * dv + bias[2 * cl + 1];

  if (p != 0) return;  // lanes 0..15 hold the result

  if (MODE == 0) {
    __half2 o = __floats2half2_rn(fmaxf(vx, 0.0f), fmaxf(vy, 0.0f));
    ((__half2*)(hout + (size_t)node * 64 + HALF * 32))[cl] = o;
  } else if (MODE == 2) {
    float2 o; o.x = vx; o.y = vy;
    ((float2*)(dout + (size_t)node * 64 + HALF * 32))[cl] = o;
  } else if (MODE == 1 && HALF == 0) {
    // mean
    const int NZ = n * 32;
    float2 o; o.x = vx; o.y = vy;
    ((float2*)(dout + NZ + (size_t)node * 32))[cl] = o;
  } else {
    // logvar + z
    const int NZ = n * 32;
    float2 o; o.x = vx; o.y = vy;
    ((float2*)(dout + 2 * NZ + (size_t)node * 32))[cl] = o;
    float2 mv = ((const float2*)(dout + NZ + (size_t)node * 32))[cl];
    int j = node * 32 + 2 * cl;
    float n0 = jax_normal_at((unsigned)j);
    float n1 = jax_normal_at((unsigned)(j + 1));
    float2 z;
    z.x = fmaf(n0, expf(0.5f * vx), mv.x);
    z.y = fmaf(n1, expf(0.5f * vy), mv.y);
    ((float2*)(dout + (size_t)node * 32))[cl] = z;
  }
}

// ---------------- launch ----------------

extern "C" void kernel_launch(void* const* d_in, const int* in_sizes, int n_in,
                              void* d_out, int out_size, void* d_ws, size_t ws_size,
                              hipStream_t stream) {
  const float* feat = (const float*)d_in[0];
  const float* cond = (const float*)d_in[1];
  const int*   eidx = (const int*)d_in[2];
  const float* W1  = (const float*)d_in[3];
  const float* b1  = (const float*)d_in[4];
  const float* Wm  = (const float*)d_in[5];
  const float* bm  = (const float*)d_in[6];
  const float* Wlv = (const float*)d_in[7];
  const float* blv = (const float*)d_in[8];
  const float* Wd  = (const float*)d_in[9];
  const float* bd  = (const float*)d_in[10];
  const float* Wo  = (const float*)d_in[11];
  const float* bo  = (const float*)d_in[12];

  const int n  = in_sizes[0] / 64;   // 50000
  const int ne = in_sizes[2] / 2;    // 800000
  const int* srcI = eidx;
  const int* dstI = eidx + ne;
  const int nbuck = (n + 255) >> 8;  // 196

  // workspace carve-up
  int*   cnt    = (int*)d_ws;                     // n
  int*   rowptr = cnt + n;                        // n+1
  int*   bsum   = rowptr + n + 1;                 // 256
  int*   boff   = bsum + 256;                     // 256
  int*   bcur   = boff + 256;                     // 256
  float* dinv   = (float*)(bcur + 256 + 3);       // n
  __half* xwA   = (__half*)(dinv + n);            // n*32
  __half* xwB   = xwA + (size_t)n * 32;           // n*32
  __half* h     = xwB + (size_t)n * 32;           // n*64
  unsigned short* ssrc = (unsigned short*)(h + (size_t)n * 64); // ne
  unsigned* coarse = (unsigned*)(ssrc + ne + (ne & 1));         // ne

  float* dout   = (float*)d_out;
  float* zbuf   = dout;                        // n*32
  float* outbuf = dout + (size_t)3 * n * 32;   // n*64

  const int BT = 256;
  auto blk = [](long long t) { return (int)((t + 255) / 256); };
  const int nb_n  = blk(n);
  const int nb_e  = blk(ne);
  const int nb_sc = (n + 1023) / 1024;
  const int nb_gw = blk((long long)n * 64);
  const int nb_g  = (n + 127) / 128;
  const int nb_fa = (ne + EPB - 1) / EPB;

  // ---- CSR setup ----
  hipLaunchKernelGGL(zero_i_kernel, dim3(nb_n), dim3(BT), 0, stream, cnt, n);
  hipLaunchKernelGGL(degree_i_kernel, dim3(nb_e), dim3(BT), 0, stream, dstI, cnt, ne);
  hipLaunchKernelGGL(scan1_kernel, dim3(nb_sc), dim3(BT), 0, stream, cnt, rowptr, bsum, n);
  hipLaunchKernelGGL(scanP_kernel, dim3(1), dim3(BT), 0, stream, bsum, boff, nb_sc, rowptr, n, ne);
  hipLaunchKernelGGL(scan2_kernel, dim3(nb_n), dim3(BT), 0, stream, rowptr, boff, cnt, dinv, bcur, n);
  hipLaunchKernelGGL(fillA_kernel, dim3(nb_fa), dim3(BT), 0, stream, srcI, dstI, bcur, coarse, ne);
  hipLaunchKernelGGL(fillB_kernel, dim3(nbuck), dim3(BT), 0, stream, coarse, rowptr, ssrc, n, ne);

  // ---- encoder conv1: h = relu(gcn(concat(feat,cond), W1, b1)) ----
  hipLaunchKernelGGL((gemm_mfma_kernel<64, 32, false, false>), dim3(nb_g), dim3(BT), 0, stream,
                     feat, cond, W1, nullptr, dinv, xwA, xwB, n);
  hipLaunchKernelGGL((gatherH_kernel<0, 0>), dim3(nb_gw), dim3(BT), 0, stream,
                     rowptr, ssrc, xwA, dinv, b1, nullptr, h, n);
  hipLaunchKernelGGL((gatherH_kernel<0, 1>), dim3(nb_gw), dim3(BT), 0, stream,
                     rowptr, ssrc, xwB, dinv, b1 + 32, nullptr, h, n);

  // ---- mean/logvar packed conv + reparam z ----
  hipLaunchKernelGGL((gemm_mfma_kernel<64, 0, true, true>), dim3(nb_g), dim3(BT), 0, stream,
                     h, nullptr, Wm, Wlv, dinv, xwA, xwB, n);
  hipLaunchKernelGGL((gatherH_kernel<1, 0>), dim3(nb_gw), dim3(BT), 0, stream,
                     rowptr, ssrc, xwA, dinv, bm, dout, nullptr, n);
  hipLaunchKernelGGL((gatherH_kernel<1, 1>), dim3(nb_gw), dim3(BT), 0, stream,
                     rowptr, ssrc, xwB, dinv, blv, dout, nullptr, n);

  // ---- decoder conv1: hd = relu(gcn(concat(z,cond), Wd, bd)) ----
  hipLaunchKernelGGL((gemm_mfma_kernel<32, 32, false, false>), dim3(nb_g), dim3(BT), 0, stream,
                     zbuf, cond, Wd, nullptr, dinv, xwA, xwB, n);
  hipLaunchKernelGGL((gatherH_kernel<0, 0>), dim3(nb_gw), dim3(BT), 0, stream,
                     rowptr, ssrc, xwA, dinv, bd, nullptr, h, n);
  hipLaunchKernelGGL((gatherH_kernel<0, 1>), dim3(nb_gw), dim3(BT), 0, stream,
                     rowptr, ssrc, xwB, dinv, bd + 32, nullptr, h, n);

  // ---- decoder out conv ----
  hipLaunchKernelGGL((gemm_mfma_kernel<64, 0, true, false>), dim3(nb_g), dim3(BT), 0, stream,
                     h, nullptr, Wo, nullptr, dinv, xwA, xwB, n);
  hipLaunchKernelGGL((gatherH_kernel<2, 0>), dim3(nb_gw), dim3(BT), 0, stream,
                     rowptr, ssrc, xwA, dinv, bo, outbuf, nullptr, n);
  hipLaunchKernelGGL((gatherH_kernel<2, 1>), dim3(nb_gw), dim3(BT), 0, stream,
                     rowptr, ssrc, xwB, dinv, bo + 32, outbuf, nullptr, n);
}

// Round 11
// 231.186 us; speedup vs baseline: 1.2626x; 1.2626x over previous
//
#include <hip/hip_runtime.h>
#include <hip/hip_bf16.h>
#include <hip/hip_fp16.h>
#include <math.h>

typedef _Float16 f16;
typedef __attribute__((ext_vector_type(8))) _Float16 f16x8;
typedef __attribute__((ext_vector_type(4))) float f32x4;

// ---------------- JAX threefry2x32 (partitionable) + normal ----------------

static __device__ __forceinline__ unsigned rotl32(unsigned x, int d) {
  return (x << d) | (x >> (32 - d));
}

// key = (0, 42)  == jax.random.key(42)
static __device__ __forceinline__ void threefry_0_42(unsigned& x0, unsigned& x1) {
  const unsigned ks0 = 0u, ks1 = 42u, ks2 = 0u ^ 42u ^ 0x1BD11BDAu;
  x0 += ks0; x1 += ks1;
#define TF_R(r) { x0 += x1; x1 = rotl32(x1, (r)); x1 ^= x0; }
  TF_R(13) TF_R(15) TF_R(26) TF_R(6)
  x0 += ks1; x1 += ks2 + 1u;
  TF_R(17) TF_R(29) TF_R(16) TF_R(24)
  x0 += ks2; x1 += ks0 + 2u;
  TF_R(13) TF_R(15) TF_R(26) TF_R(6)
  x0 += ks0; x1 += ks1 + 3u;
  TF_R(17) TF_R(29) TF_R(16) TF_R(24)
  x0 += ks1; x1 += ks2 + 4u;
  TF_R(13) TF_R(15) TF_R(26) TF_R(6)
  x0 += ks2; x1 += ks0 + 5u;
#undef TF_R
}

static __device__ __forceinline__ float erfinv_f(float u) {
  float w = -logf((1.0f - u) * (1.0f + u));
  float p;
  if (w < 5.0f) {
    w = w - 2.5f;
    p = 2.81022636e-08f;
    p = fmaf(p, w, 3.43273939e-07f);
    p = fmaf(p, w, -3.5233877e-06f);
    p = fmaf(p, w, -4.39150654e-06f);
    p = fmaf(p, w, 0.00021858087f);
    p = fmaf(p, w, -0.00125372503f);
    p = fmaf(p, w, -0.00417768164f);
    p = fmaf(p, w, 0.246640727f);
    p = fmaf(p, w, 1.50140941f);
  } else {
    w = sqrtf(w) - 3.0f;
    p = -0.000200214257f;
    p = fmaf(p, w, 0.000100950558f);
    p = fmaf(p, w, 0.00134934322f);
    p = fmaf(p, w, -0.00367342844f);
    p = fmaf(p, w, 0.00573950773f);
    p = fmaf(p, w, -0.0076224613f);
    p = fmaf(p, w, 0.00943887047f);
    p = fmaf(p, w, 1.00167406f);
    p = fmaf(p, w, 2.83297682f);
  }
  return p * u;
}

// jax_threefry_partitionable=True: bits(j) = xor(threefry2x32(key, (0, j)))
static __device__ __forceinline__ float jax_normal_at(unsigned j) {
  unsigned x0 = 0u, x1 = j;
  threefry_0_42(x0, x1);
  unsigned bits = x0 ^ x1;
  float f = __uint_as_float((bits >> 9) | 0x3f800000u) - 1.0f;   // [0,1)
  float u = fmaf(f, 1.99999994f, -0.99999994f);
  return 1.41421356237f * erfinv_f(u);
}

// ---------------- setup kernels ----------------

__global__ void degree_i_kernel(const int* __restrict__ dstI, int* __restrict__ cnt, int ne) {
  int e = blockIdx.x * blockDim.x + threadIdx.x;
  if (e < ne) atomicAdd(&cnt[dstI[e]], 1);
}

// per-bucket sums: bh[b] = sum cnt[b*256 .. b*256+255]
__global__ __launch_bounds__(256) void bsum_kernel(const int* __restrict__ cnt,
                                                   int* __restrict__ bh, int n) {
  __shared__ int s[256];
  int i = blockIdx.x * 256 + threadIdx.x;
  s[threadIdx.x] = (i < n) ? cnt[i] : 0;
  __syncthreads();
  for (int off = 128; off > 0; off >>= 1) {
    if (threadIdx.x < off) s[threadIdx.x] += s[threadIdx.x + off];
    __syncthreads();
  }
  if (threadIdx.x == 0) bh[blockIdx.x] = s[0];
}

// each block: scan bh (redundant, 196 vals) for its bucket base; block-scan its
// 256 counts -> rowptr; dinv; bcur[b] = bucket base; last block sets rowptr[n].
__global__ __launch_bounds__(256) void scanN_kernel(const int* __restrict__ cnt,
                                                    const int* __restrict__ bh,
                                                    int* __restrict__ rowptr,
                                                    float* __restrict__ dinv,
                                                    int* __restrict__ bcur,
                                                    int n, int ne, int nbuck) {
  __shared__ int sb[256];
  __shared__ int sc[256];
  __shared__ int basesh;
  const int t = threadIdx.x;
  const int b = blockIdx.x;
  sb[t] = (t < nbuck) ? bh[t] : 0;
  __syncthreads();
  for (int off = 1; off < 256; off <<= 1) {
    int x = (t >= off) ? sb[t - off] : 0;
    __syncthreads();
    sb[t] += x;
    __syncthreads();
  }
  if (t == 0) basesh = (b > 0) ? sb[b - 1] : 0;
  __syncthreads();

  int i = b * 256 + t;
  int v = (i < n) ? cnt[i] : 0;
  sc[t] = v;
  __syncthreads();
  for (int off = 1; off < 256; off <<= 1) {
    int x = (t >= off) ? sc[t - off] : 0;
    __syncthreads();
    sc[t] += x;
    __syncthreads();
  }
  const int base = basesh;
  if (i < n) {
    rowptr[i] = base + sc[t] - v;
    dinv[i] = 1.0f / sqrtf((float)v + 1.0f);
  }
  if (t == 0) bcur[b] = base;
  if (b == nbuck - 1 && t == 255) rowptr[n] = ne;
}

// ---------------- two-pass binned fill ----------------
#define EPB 2048
__global__ __launch_bounds__(256) void fillA_kernel(
    const int* __restrict__ srcI, const int* __restrict__ dstI,
    int* __restrict__ bcur, unsigned* __restrict__ coarse, int ne) {
  __shared__ int hist[256], hpre[256], hcur[256], gbase[256];
  __shared__ unsigned st[EPB];
  const int tid = threadIdx.x;
  const int base = blockIdx.x * EPB;

  hist[tid] = 0; hcur[tid] = 0;
  __syncthreads();

  int s[8], d[8];
#pragma unroll
  for (int k = 0; k < 8; ++k) {
    int e = base + k * 256 + tid;
    if (e < ne) { s[k] = srcI[e]; d[k] = dstI[e]; }
    else        { s[k] = -1;      d[k] = 0; }
  }
#pragma unroll
  for (int k = 0; k < 8; ++k)
    if (s[k] >= 0) atomicAdd(&hist[d[k] >> 8], 1);
  __syncthreads();

  int hv = hist[tid];
  hpre[tid] = hv;
  __syncthreads();
  for (int off = 1; off < 256; off <<= 1) {
    int x = (tid >= off) ? hpre[tid - off] : 0;
    __syncthreads();
    hpre[tid] += x;
    __syncthreads();
  }

#pragma unroll
  for (int k = 0; k < 8; ++k) {
    if (s[k] >= 0) {
      int b = d[k] >> 8;
      int pos = (hpre[b] - hist[b]) + atomicAdd(&hcur[b], 1);
      st[pos] = ((unsigned)b << 24) | ((unsigned)(d[k] & 255) << 16) | (unsigned)s[k];
    }
  }
  if (hist[tid] > 0) gbase[tid] = atomicAdd(&bcur[tid], hist[tid]);
  __syncthreads();

  int cntE = ne - base; if (cntE > EPB) cntE = EPB;
  for (int i = tid; i < cntE; i += 256) {
    unsigned v = st[i];
    int b = v >> 24;
    int excl = hpre[b] - hist[b];
    coarse[gbase[b] + (i - excl)] = v & 0x00FFFFFFu;
  }
}

__global__ __launch_bounds__(256) void fillB_kernel(
    const unsigned* __restrict__ coarse, const int* __restrict__ rowptr,
    unsigned short* __restrict__ ssrc, int n, int ne) {
  __shared__ int rcur[256];
  const int b = blockIdx.x;
  const int r0 = b << 8;
  const int tid = threadIdx.x;
  if (r0 + tid < n) rcur[tid] = rowptr[r0 + tid];
  const int e0 = rowptr[r0];
  const int e1 = (r0 + 256 <= n) ? rowptr[r0 + 256] : ne;
  __syncthreads();
  for (int e = e0 + tid; e < e1; e += 256) {
    unsigned v = coarse[e];
    int r = (v >> 16) & 255;
    int pos = atomicAdd(&rcur[r], 1);
    ssrc[pos] = (unsigned short)(v & 0xFFFFu);
  }
}

// ---------------- MFMA GEMM: Y[n][64] = fp16(concat(X1,X2)) @ fp16(W) * dinv ----------------
// 128 nodes/block, 4 waves; wave = 32 rows x 64 cols; K-step 32 via mfma_f32_16x16x32_f16.
template<int IN1, int IN2, bool X1HALF, bool DUALW>
__global__ __launch_bounds__(256) void gemm_mfma_kernel(
    const void* __restrict__ X1v, const float* __restrict__ X2,
    const float* __restrict__ Wa, const float* __restrict__ Wb,
    const float* __restrict__ dinv, __half* __restrict__ Y, int n) {
  constexpr int IN = IN1 + IN2;
  constexpr int IP = IN + 8;
  __shared__ f16 xs[128 * IP];
  __shared__ f16 wt[64 * IP];  // W transposed: wt[col][k]

  const int tid = threadIdx.x;
  const int base = blockIdx.x * 128;

  for (int i = tid; i < IN * 64; i += 256) {
    int k = i >> 6, c = i & 63;
    float w;
    if (DUALW) w = (c < 32) ? Wa[k * 32 + c] : Wb[k * 32 + (c - 32)];
    else       w = Wa[i];
    wt[c * IP + k] = (f16)w;
  }
  if (X1HALF) {
    const __half* X1 = (const __half*)X1v;
    for (int idx = tid; idx < 128 * (IN1 / 8); idx += 256) {
      int node = idx / (IN1 / 8);
      int k8 = (idx % (IN1 / 8)) * 8;
      int g = base + node;
      f16x8 v = {};
      if (g < n) v = *(const f16x8*)(X1 + (size_t)g * IN1 + k8);
      *(f16x8*)&xs[node * IP + k8] = v;
    }
  } else {
    const float* X1 = (const float*)X1v;
    for (int idx = tid; idx < 128 * (IN1 / 4); idx += 256) {
      int node = idx / (IN1 / 4);
      int k4 = (idx % (IN1 / 4)) * 4;
      int g = base + node;
      float4 v = (g < n) ? *(const float4*)(X1 + (size_t)g * IN1 + k4)
                         : make_float4(0.f, 0.f, 0.f, 0.f);
      f16* p = &xs[node * IP + k4];
      p[0] = (f16)v.x; p[1] = (f16)v.y; p[2] = (f16)v.z; p[3] = (f16)v.w;
    }
  }
  if (IN2 > 0) {
    for (int idx = tid; idx < 128 * (IN2 / 4); idx += 256) {
      int node = idx / (IN2 / 4);
      int k4 = (idx % (IN2 / 4)) * 4;
      int g = base + node;
      float4 v = (g < n) ? *(const float4*)(X2 + (size_t)g * IN2 + k4)
                         : make_float4(0.f, 0.f, 0.f, 0.f);
      f16* p = &xs[node * IP + IN1 + k4];
      p[0] = (f16)v.x; p[1] = (f16)v.y; p[2] = (f16)v.z; p[3] = (f16)v.w;
    }
  }
  __syncthreads();

  const int wid  = tid >> 6;
  const int lane = tid & 63;
  const int l15  = lane & 15;
  const int lk8  = (lane >> 4) * 8;

  f32x4 acc[2][4] = {{{0.f,0.f,0.f,0.f}}};
  constexpr int KB = IN / 32;
#pragma unroll
  for (int kb = 0; kb < KB; ++kb) {
    const int k0 = kb * 32 + lk8;
    f16x8 a0 = *(const f16x8*)&xs[(wid * 32 +      l15) * IP + k0];
    f16x8 a1 = *(const f16x8*)&xs[(wid * 32 + 16 + l15) * IP + k0];
#pragma unroll
    for (int ct = 0; ct < 4; ++ct) {
      f16x8 b = *(const f16x8*)&wt[(ct * 16 + l15) * IP + k0];
      acc[0][ct] = __builtin_amdgcn_mfma_f32_16x16x32_f16(a0, b, acc[0][ct], 0, 0, 0);
      acc[1][ct] = __builtin_amdgcn_mfma_f32_16x16x32_f16(a1, b, acc[1][ct], 0, 0, 0);
    }
  }

#pragma unroll
  for (int rt = 0; rt < 2; ++rt) {
#pragma unroll
    for (int i = 0; i < 4; ++i) {
      int node = base + wid * 32 + rt * 16 + (lane >> 4) * 4 + i;
      if (node < n) {
        float dv = dinv[node];
#pragma unroll
        for (int ct = 0; ct < 4; ++ct) {
          Y[(size_t)node * 64 + ct * 16 + l15] = __float2half(acc[rt][ct][i] * dv);
        }
      }
    }
  }
}

// ---------------- CSR gather + fused finalize (half2 lanes, 8-deep ILP) ----------------
// MODE 0: +bias, relu -> __half out. MODE 1: mean||logvar -> z/mean/logvar (fp32).
// MODE 2: +bias -> fp32 out.
template<int MODE>
__global__ __launch_bounds__(256) void gather_kernel(
    const int* __restrict__ rowptr, const unsigned short* __restrict__ ssrc,
    const __half* __restrict__ xwp, const float* __restrict__ dinv,
    const float* __restrict__ b0, const float* __restrict__ b1,
    void* __restrict__ outv, int n) {
  const int node = (blockIdx.x * 256 + threadIdx.x) >> 6;
  const int lane = threadIdx.x & 63;
  if (node >= n) return;
  const int hf = lane >> 5;
  const int cl = lane & 31;

  float2 a1, a2, a3, a4;
  a2.x = a2.y = a3.x = a3.y = a4.x = a4.y = 0.f;
  {
    float2 f = __half22float2(((const __half2*)(xwp + (size_t)node * 64))[cl]);
    a1.x = hf ? 0.f : f.x;
    a1.y = hf ? 0.f : f.y;
  }

  const int beg = rowptr[node];
  const int end = rowptr[node + 1];
  for (int cbase = beg; cbase < end; cbase += 64) {
    int m = end - cbase; if (m > 64) m = 64;
    unsigned sv = (lane < m) ? (unsigned)ssrc[cbase + lane] : 0u;
    int k = 0;
    for (; k + 7 < m; k += 8) {
      unsigned sa = __shfl(sv, k + 0 + hf, 64);
      unsigned sb = __shfl(sv, k + 2 + hf, 64);
      unsigned sc = __shfl(sv, k + 4 + hf, 64);
      unsigned sd = __shfl(sv, k + 6 + hf, 64);
      float2 fa = __half22float2(((const __half2*)(xwp + (size_t)sa * 64))[cl]);
      float2 fb = __half22float2(((const __half2*)(xwp + (size_t)sb * 64))[cl]);
      float2 fc = __half22float2(((const __half2*)(xwp + (size_t)sc * 64))[cl]);
      float2 fd = __half22float2(((const __half2*)(xwp + (size_t)sd * 64))[cl]);
      a1.x += fa.x; a1.y += fa.y;
      a2.x += fb.x; a2.y += fb.y;
      a3.x += fc.x; a3.y += fc.y;
      a4.x += fd.x; a4.y += fd.y;
    }
    for (; k + 1 < m; k += 2) {
      unsigned sa = __shfl(sv, k + hf, 64);
      float2 fa = __half22float2(((const __half2*)(xwp + (size_t)sa * 64))[cl]);
      a1.x += fa.x; a1.y += fa.y;
    }
    if (k < m) {
      unsigned sa = __shfl(sv, k, 64);
      if (hf == 0) {
        float2 fa = __half22float2(((const __half2*)(xwp + (size_t)sa * 64))[cl]);
        a1.x += fa.x; a1.y += fa.y;
      }
    }
  }
  float2 acc;
  acc.x = (a1.x + a2.x) + (a3.x + a4.x);
  acc.y = (a1.y + a2.y) + (a3.y + a4.y);
  acc.x += __shfl(acc.x, lane ^ 32, 64);
  acc.y += __shfl(acc.y, lane ^ 32, 64);
  float dv = dinv[node];
  float vx = acc.x * dv, vy = acc.y * dv;

  if (hf != 0) return;

  const int c0 = 2 * cl;
  if (MODE == 0) {
    __half* out = (__half*)outv;
    __half2 o = __floats2half2_rn(fmaxf(vx + b0[c0], 0.0f), fmaxf(vy + b0[c0 + 1], 0.0f));
    ((__half2*)(out + (size_t)node * 64))[cl] = o;
  } else if (MODE == 2) {
    float* out = (float*)outv;
    float2 o;
    o.x = vx + b0[c0];
    o.y = vy + b0[c0 + 1];
    ((float2*)(out + (size_t)node * 64))[cl] = o;
  } else {
    float* out = (float*)outv;
    float bx = (c0 < 32) ? b0[c0] : b1[c0 - 32];
    float by = (c0 + 1 < 32) ? b0[c0 + 1] : b1[c0 + 1 - 32];
    vx += bx; vy += by;
    float ox = __shfl(vx, lane + 16, 64);
    float oy = __shfl(vy, lane + 16, 64);
    const int NZ = n * 32;
    if (cl < 16) {
      int j = node * 32 + c0;
      float n0 = jax_normal_at((unsigned)j);
      float n1 = jax_normal_at((unsigned)(j + 1));
      out[j]     = fmaf(n0, expf(0.5f * ox), vx);  // z
      out[j + 1] = fmaf(n1, expf(0.5f * oy), vy);
      out[NZ + j]     = vx;                        // mean
      out[NZ + j + 1] = vy;
    } else {
      int j = node * 32 + (c0 - 32);
      out[2 * NZ + j]     = vx;                    // logvar
      out[2 * NZ + j + 1] = vy;
    }
  }
}

// ---------------- launch ----------------

extern "C" void kernel_launch(void* const* d_in, const int* in_sizes, int n_in,
                              void* d_out, int out_size, void* d_ws, size_t ws_size,
                              hipStream_t stream) {
  const float* feat = (const float*)d_in[0];
  const float* cond = (const float*)d_in[1];
  const int*   eidx = (const int*)d_in[2];
  const float* W1  = (const float*)d_in[3];
  const float* b1  = (const float*)d_in[4];
  const float* Wm  = (const float*)d_in[5];
  const float* bm  = (const float*)d_in[6];
  const float* Wlv = (const float*)d_in[7];
  const float* blv = (const float*)d_in[8];
  const float* Wd  = (const float*)d_in[9];
  const float* bd  = (const float*)d_in[10];
  const float* Wo  = (const float*)d_in[11];
  const float* bo  = (const float*)d_in[12];

  const int n  = in_sizes[0] / 64;   // 50000 (< 65536 -> ssrc fits uint16)
  const int ne = in_sizes[2] / 2;    // 800000
  const int* srcI = eidx;
  const int* dstI = eidx + ne;
  const int nbuck = (n + 255) >> 8;  // 196

  // workspace carve-up
  int*   cnt    = (int*)d_ws;                     // n
  int*   rowptr = cnt + n;                        // n+1
  int*   bh     = rowptr + n + 1;                 // 256
  int*   bcur   = bh + 256;                       // 256
  float* dinv   = (float*)(bcur + 256 + 3);       // n
  __half* xwp   = (__half*)(dinv + n);            // n*64
  __half* h     = xwp + (size_t)n * 64;           // n*64
  unsigned short* ssrc = (unsigned short*)(h + (size_t)n * 64); // ne
  unsigned* coarse = (unsigned*)(ssrc + ne + (ne & 1));         // ne

  float* dout   = (float*)d_out;
  float* zbuf   = dout;                        // n*32
  float* outbuf = dout + (size_t)3 * n * 32;   // n*64

  const int BT = 256;
  auto blk = [](long long t) { return (int)((t + 255) / 256); };
  const int nb_e  = blk(ne);
  const int nb_gw = blk((long long)n * 64);
  const int nb_g  = (n + 127) / 128;
  const int nb_fa = (ne + EPB - 1) / EPB;

  // ---- CSR setup ----
  hipMemsetAsync(cnt, 0, (size_t)n * sizeof(int), stream);
  hipLaunchKernelGGL(degree_i_kernel, dim3(nb_e), dim3(BT), 0, stream, dstI, cnt, ne);
  hipLaunchKernelGGL(bsum_kernel, dim3(nbuck), dim3(BT), 0, stream, cnt, bh, n);
  hipLaunchKernelGGL(scanN_kernel, dim3(nbuck), dim3(BT), 0, stream,
                     cnt, bh, rowptr, dinv, bcur, n, ne, nbuck);
  hipLaunchKernelGGL(fillA_kernel, dim3(nb_fa), dim3(BT), 0, stream, srcI, dstI, bcur, coarse, ne);
  hipLaunchKernelGGL(fillB_kernel, dim3(nbuck), dim3(BT), 0, stream, coarse, rowptr, ssrc, n, ne);

  // ---- encoder conv1: h = relu(gcn(concat(feat,cond), W1, b1)) ----
  hipLaunchKernelGGL((gemm_mfma_kernel<64, 32, false, false>), dim3(nb_g), dim3(BT), 0, stream,
                     feat, cond, W1, nullptr, dinv, xwp, n);
  hipLaunchKernelGGL((gather_kernel<0>), dim3(nb_gw), dim3(BT), 0, stream,
                     rowptr, ssrc, xwp, dinv, b1, nullptr, h, n);

  // ---- mean/logvar packed conv + reparam z ----
  hipLaunchKernelGGL((gemm_mfma_kernel<64, 0, true, true>), dim3(nb_g), dim3(BT), 0, stream,
                     h, nullptr, Wm, Wlv, dinv, xwp, n);
  hipLaunchKernelGGL((gather_kernel<1>), dim3(nb_gw), dim3(BT), 0, stream,
                     rowptr, ssrc, xwp, dinv, bm, blv, dout, n);

  // ---- decoder conv1: hd = relu(gcn(concat(z,cond), Wd, bd)) ----
  hipLaunchKernelGGL((gemm_mfma_kernel<32, 32, false, false>), dim3(nb_g), dim3(BT), 0, stream,
                     zbuf, cond, Wd, nullptr, dinv, xwp, n);
  hipLaunchKernelGGL((gather_kernel<0>), dim3(nb_gw), dim3(BT), 0, stream,
                     rowptr, ssrc, xwp, dinv, bd, nullptr, h, n);

  // ---- decoder out conv ----
  hipLaunchKernelGGL((gemm_mfma_kernel<64, 0, true, false>), dim3(nb_g), dim3(BT), 0, stream,
                     h, nullptr, Wo, nullptr, dinv, xwp, n);
  hipLaunchKernelGGL((gather_kernel<2>), dim3(nb_gw), dim3(BT), 0, stream,
                     rowptr, ssrc, xwp, dinv, bo, nullptr, outbuf, n);
}

// Round 12
// 227.466 us; speedup vs baseline: 1.2832x; 1.0164x over previous
//
#include <hip/hip_runtime.h>
#include <hip/hip_bf16.h>
#include <hip/hip_fp16.h>
#include <math.h>

typedef _Float16 f16;
typedef __attribute__((ext_vector_type(8))) _Float16 f16x8;
typedef __attribute__((ext_vector_type(4))) float f32x4;

#define NQ 4          // src quartiles for cache-locality edge ordering
#define QDIV 12500    // n / NQ

// ---------------- JAX threefry2x32 (partitionable) + normal ----------------

static __device__ __forceinline__ unsigned rotl32(unsigned x, int d) {
  return (x << d) | (x >> (32 - d));
}

// key = (0, 42)  == jax.random.key(42)
static __device__ __forceinline__ void threefry_0_42(unsigned& x0, unsigned& x1) {
  const unsigned ks0 = 0u, ks1 = 42u, ks2 = 0u ^ 42u ^ 0x1BD11BDAu;
  x0 += ks0; x1 += ks1;
#define TF_R(r) { x0 += x1; x1 = rotl32(x1, (r)); x1 ^= x0; }
  TF_R(13) TF_R(15) TF_R(26) TF_R(6)
  x0 += ks1; x1 += ks2 + 1u;
  TF_R(17) TF_R(29) TF_R(16) TF_R(24)
  x0 += ks2; x1 += ks0 + 2u;
  TF_R(13) TF_R(15) TF_R(26) TF_R(6)
  x0 += ks0; x1 += ks1 + 3u;
  TF_R(17) TF_R(29) TF_R(16) TF_R(24)
  x0 += ks1; x1 += ks2 + 4u;
  TF_R(13) TF_R(15) TF_R(26) TF_R(6)
  x0 += ks2; x1 += ks0 + 5u;
#undef TF_R
}

static __device__ __forceinline__ float erfinv_f(float u) {
  float w = -logf((1.0f - u) * (1.0f + u));
  float p;
  if (w < 5.0f) {
    w = w - 2.5f;
    p = 2.81022636e-08f;
    p = fmaf(p, w, 3.43273939e-07f);
    p = fmaf(p, w, -3.5233877e-06f);
    p = fmaf(p, w, -4.39150654e-06f);
    p = fmaf(p, w, 0.00021858087f);
    p = fmaf(p, w, -0.00125372503f);
    p = fmaf(p, w, -0.00417768164f);
    p = fmaf(p, w, 0.246640727f);
    p = fmaf(p, w, 1.50140941f);
  } else {
    w = sqrtf(w) - 3.0f;
    p = -0.000200214257f;
    p = fmaf(p, w, 0.000100950558f);
    p = fmaf(p, w, 0.00134934322f);
    p = fmaf(p, w, -0.00367342844f);
    p = fmaf(p, w, 0.00573950773f);
    p = fmaf(p, w, -0.0076224613f);
    p = fmaf(p, w, 0.00943887047f);
    p = fmaf(p, w, 1.00167406f);
    p = fmaf(p, w, 2.83297682f);
  }
  return p * u;
}

// jax_threefry_partitionable=True: bits(j) = xor(threefry2x32(key, (0, j)))
static __device__ __forceinline__ float jax_normal_at(unsigned j) {
  unsigned x0 = 0u, x1 = j;
  threefry_0_42(x0, x1);
  unsigned bits = x0 ^ x1;
  float f = __uint_as_float((bits >> 9) | 0x3f800000u) - 1.0f;   // [0,1)
  float u = fmaf(f, 1.99999994f, -0.99999994f);
  return 1.41421356237f * erfinv_f(u);
}

// ---------------- setup kernels ----------------

// per-(row, src-quartile) degree counts: cntQ[d*4 + src/QDIV]
__global__ void degree_i_kernel(const int* __restrict__ srcI, const int* __restrict__ dstI,
                                int* __restrict__ cntQ, int ne) {
  int e = blockIdx.x * blockDim.x + threadIdx.x;
  if (e < ne) {
    int s = srcI[e], d = dstI[e];
    atomicAdd(&cntQ[d * NQ + s / QDIV], 1);
  }
}

// per-bucket sums: bh[b] = total edges of rows [b*256, b*256+256)
__global__ __launch_bounds__(256) void bsum_kernel(const int* __restrict__ cntQ,
                                                   int* __restrict__ bh, int n) {
  __shared__ int s[256];
  int i4 = blockIdx.x * 1024 + threadIdx.x * 4;  // 4 ints per row
  int v = 0;
  if (i4 < n * NQ) {
    int4 q = *(const int4*)(cntQ + i4);
    v = q.x + q.y + q.z + q.w;
  }
  s[threadIdx.x] = v;
  __syncthreads();
  for (int off = 128; off > 0; off >>= 1) {
    if (threadIdx.x < off) s[threadIdx.x] += s[threadIdx.x + off];
    __syncthreads();
  }
  if (threadIdx.x == 0) bh[blockIdx.x] = s[0];
}

// each block: scan bh (redundant) for its bucket base; block-scan its 256 row
// totals -> rowptr; dinv; bcur[b] = bucket base; last block sets rowptr[n].
__global__ __launch_bounds__(256) void scanN_kernel(const int* __restrict__ cntQ,
                                                    const int* __restrict__ bh,
                                                    int* __restrict__ rowptr,
                                                    float* __restrict__ dinv,
                                                    int* __restrict__ bcur,
                                                    int n, int ne, int nbuck) {
  __shared__ int sb[256];
  __shared__ int sc[256];
  __shared__ int basesh;
  const int t = threadIdx.x;
  const int b = blockIdx.x;
  sb[t] = (t < nbuck) ? bh[t] : 0;
  __syncthreads();
  for (int off = 1; off < 256; off <<= 1) {
    int x = (t >= off) ? sb[t - off] : 0;
    __syncthreads();
    sb[t] += x;
    __syncthreads();
  }
  if (t == 0) basesh = (b > 0) ? sb[b - 1] : 0;
  __syncthreads();

  int i = b * 256 + t;
  int v = 0;
  if (i < n) {
    int4 q = *(const int4*)(cntQ + i * NQ);
    v = q.x + q.y + q.z + q.w;
  }
  sc[t] = v;
  __syncthreads();
  for (int off = 1; off < 256; off <<= 1) {
    int x = (t >= off) ? sc[t - off] : 0;
    __syncthreads();
    sc[t] += x;
    __syncthreads();
  }
  const int base = basesh;
  if (i < n) {
    rowptr[i] = base + sc[t] - v;
    dinv[i] = 1.0f / sqrtf((float)v + 1.0f);
  }
  if (t == 0) bcur[b] = base;
  if (b == nbuck - 1 && t == 255) rowptr[n] = ne;
}

// ---------------- two-pass binned fill ----------------
#define EPB 2048
__global__ __launch_bounds__(256) void fillA_kernel(
    const int* __restrict__ srcI, const int* __restrict__ dstI,
    int* __restrict__ bcur, unsigned* __restrict__ coarse, int ne) {
  __shared__ int hist[256], hpre[256], hcur[256], gbase[256];
  __shared__ unsigned st[EPB];
  const int tid = threadIdx.x;
  const int base = blockIdx.x * EPB;

  hist[tid] = 0; hcur[tid] = 0;
  __syncthreads();

  int s[8], d[8];
#pragma unroll
  for (int k = 0; k < 8; ++k) {
    int e = base + k * 256 + tid;
    if (e < ne) { s[k] = srcI[e]; d[k] = dstI[e]; }
    else        { s[k] = -1;      d[k] = 0; }
  }
#pragma unroll
  for (int k = 0; k < 8; ++k)
    if (s[k] >= 0) atomicAdd(&hist[d[k] >> 8], 1);
  __syncthreads();

  int hv = hist[tid];
  hpre[tid] = hv;
  __syncthreads();
  for (int off = 1; off < 256; off <<= 1) {
    int x = (tid >= off) ? hpre[tid - off] : 0;
    __syncthreads();
    hpre[tid] += x;
    __syncthreads();
  }

#pragma unroll
  for (int k = 0; k < 8; ++k) {
    if (s[k] >= 0) {
      int b = d[k] >> 8;
      int pos = (hpre[b] - hist[b]) + atomicAdd(&hcur[b], 1);
      st[pos] = ((unsigned)b << 24) | ((unsigned)(d[k] & 255) << 16) | (unsigned)s[k];
    }
  }
  if (hist[tid] > 0) gbase[tid] = atomicAdd(&bcur[tid], hist[tid]);
  __syncthreads();

  int cntE = ne - base; if (cntE > EPB) cntE = EPB;
  for (int i = tid; i < cntE; i += 256) {
    unsigned v = st[i];
    int b = v >> 24;
    int excl = hpre[b] - hist[b];
    coarse[gbase[b] + (i - excl)] = v & 0x00FFFFFFu;
  }
}

// one block per bucket; 4 src-quartile cursors per row -> rows stored
// [q0 edges][q1][q2][q3]; block owns its ssrc region exclusively.
__global__ __launch_bounds__(256) void fillB_kernel(
    const unsigned* __restrict__ coarse, const int* __restrict__ rowptr,
    const int* __restrict__ cntQ, unsigned short* __restrict__ ssrc, int n, int ne) {
  __shared__ int rcur[NQ * 256];
  const int b = blockIdx.x;
  const int r0 = b << 8;
  const int tid = threadIdx.x;
  if (r0 + tid < n) {
    int c = rowptr[r0 + tid];
    int4 q = *(const int4*)(cntQ + (r0 + tid) * NQ);
    rcur[0 * 256 + tid] = c;
    rcur[1 * 256 + tid] = c + q.x;
    rcur[2 * 256 + tid] = c + q.x + q.y;
    rcur[3 * 256 + tid] = c + q.x + q.y + q.z;
  }
  const int e0 = rowptr[r0];
  const int e1 = (r0 + 256 <= n) ? rowptr[r0 + 256] : ne;
  __syncthreads();
  for (int e = e0 + tid; e < e1; e += 256) {
    unsigned v = coarse[e];
    int r = (v >> 16) & 255;
    int s = v & 0xFFFFu;
    int q = s / QDIV;
    int pos = atomicAdd(&rcur[q * 256 + r], 1);
    ssrc[pos] = (unsigned short)s;
  }
}

// ---------------- MFMA GEMM: Y[n][64] = fp16(concat(X1,X2)) @ fp16(W) * dinv ----------------
// 128 nodes/block, 4 waves; wave = 32 rows x 64 cols; K-step 32 via mfma_f32_16x16x32_f16.
template<int IN1, int IN2, bool X1HALF, bool DUALW>
__global__ __launch_bounds__(256) void gemm_mfma_kernel(
    const void* __restrict__ X1v, const float* __restrict__ X2,
    const float* __restrict__ Wa, const float* __restrict__ Wb,
    const float* __restrict__ dinv, __half* __restrict__ Y, int n) {
  constexpr int IN = IN1 + IN2;
  constexpr int IP = IN + 8;
  __shared__ f16 xs[128 * IP];
  __shared__ f16 wt[64 * IP];  // W transposed: wt[col][k]

  const int tid = threadIdx.x;
  const int base = blockIdx.x * 128;

  for (int i = tid; i < IN * 64; i += 256) {
    int k = i >> 6, c = i & 63;
    float w;
    if (DUALW) w = (c < 32) ? Wa[k * 32 + c] : Wb[k * 32 + (c - 32)];
    else       w = Wa[i];
    wt[c * IP + k] = (f16)w;
  }
  if (X1HALF) {
    const __half* X1 = (const __half*)X1v;
    for (int idx = tid; idx < 128 * (IN1 / 8); idx += 256) {
      int node = idx / (IN1 / 8);
      int k8 = (idx % (IN1 / 8)) * 8;
      int g = base + node;
      f16x8 v = {};
      if (g < n) v = *(const f16x8*)(X1 + (size_t)g * IN1 + k8);
      *(f16x8*)&xs[node * IP + k8] = v;
    }
  } else {
    const float* X1 = (const float*)X1v;
    for (int idx = tid; idx < 128 * (IN1 / 4); idx += 256) {
      int node = idx / (IN1 / 4);
      int k4 = (idx % (IN1 / 4)) * 4;
      int g = base + node;
      float4 v = (g < n) ? *(const float4*)(X1 + (size_t)g * IN1 + k4)
                         : make_float4(0.f, 0.f, 0.f, 0.f);
      f16* p = &xs[node * IP + k4];
      p[0] = (f16)v.x; p[1] = (f16)v.y; p[2] = (f16)v.z; p[3] = (f16)v.w;
    }
  }
  if (IN2 > 0) {
    for (int idx = tid; idx < 128 * (IN2 / 4); idx += 256) {
      int node = idx / (IN2 / 4);
      int k4 = (idx % (IN2 / 4)) * 4;
      int g = base + node;
      float4 v = (g < n) ? *(const float4*)(X2 + (size_t)g * IN2 + k4)
                         : make_float4(0.f, 0.f, 0.f, 0.f);
      f16* p = &xs[node * IP + IN1 + k4];
      p[0] = (f16)v.x; p[1] = (f16)v.y; p[2] = (f16)v.z; p[3] = (f16)v.w;
    }
  }
  __syncthreads();

  const int wid  = tid >> 6;
  const int lane = tid & 63;
  const int l15  = lane & 15;
  const int lk8  = (lane >> 4) * 8;

  f32x4 acc[2][4] = {{{0.f,0.f,0.f,0.f}}};
  constexpr int KB = IN / 32;
#pragma unroll
  for (int kb = 0; kb < KB; ++kb) {
    const int k0 = kb * 32 + lk8;
    f16x8 a0 = *(const f16x8*)&xs[(wid * 32 +      l15) * IP + k0];
    f16x8 a1 = *(const f16x8*)&xs[(wid * 32 + 16 + l15) * IP + k0];
#pragma unroll
    for (int ct = 0; ct < 4; ++ct) {
      f16x8 b = *(const f16x8*)&wt[(ct * 16 + l15) * IP + k0];
      acc[0][ct] = __builtin_amdgcn_mfma_f32_16x16x32_f16(a0, b, acc[0][ct], 0, 0, 0);
      acc[1][ct] = __builtin_amdgcn_mfma_f32_16x16x32_f16(a1, b, acc[1][ct], 0, 0, 0);
    }
  }

#pragma unroll
  for (int rt = 0; rt < 2; ++rt) {
#pragma unroll
    for (int i = 0; i < 4; ++i) {
      int node = base + wid * 32 + rt * 16 + (lane >> 4) * 4 + i;
      if (node < n) {
        float dv = dinv[node];
#pragma unroll
        for (int ct = 0; ct < 4; ++ct) {
          Y[(size_t)node * 64 + ct * 16 + l15] = __float2half(acc[rt][ct][i] * dv);
        }
      }
    }
  }
}

// ---------------- CSR gather + fused finalize (half2 lanes, 8-deep ILP) ----------------
// MODE 0: +bias, relu -> __half out. MODE 1: mean||logvar -> z/mean/logvar (fp32).
// MODE 2: +bias -> fp32 out.
template<int MODE>
__global__ __launch_bounds__(256) void gather_kernel(
    const int* __restrict__ rowptr, const unsigned short* __restrict__ ssrc,
    const __half* __restrict__ xwp, const float* __restrict__ dinv,
    const float* __restrict__ b0, const float* __restrict__ b1,
    void* __restrict__ outv, int n) {
  const int node = (blockIdx.x * 256 + threadIdx.x) >> 6;
  const int lane = threadIdx.x & 63;
  if (node >= n) return;
  const int hf = lane >> 5;
  const int cl = lane & 31;

  float2 a1, a2, a3, a4;
  a2.x = a2.y = a3.x = a3.y = a4.x = a4.y = 0.f;
  {
    float2 f = __half22float2(((const __half2*)(xwp + (size_t)node * 64))[cl]);
    a1.x = hf ? 0.f : f.x;
    a1.y = hf ? 0.f : f.y;
  }

  const int beg = rowptr[node];
  const int end = rowptr[node + 1];
  for (int cbase = beg; cbase < end; cbase += 64) {
    int m = end - cbase; if (m > 64) m = 64;
    unsigned sv = (lane < m) ? (unsigned)ssrc[cbase + lane] : 0u;
    int k = 0;
    for (; k + 7 < m; k += 8) {
      unsigned sa = __shfl(sv, k + 0 + hf, 64);
      unsigned sb = __shfl(sv, k + 2 + hf, 64);
      unsigned sc = __shfl(sv, k + 4 + hf, 64);
      unsigned sd = __shfl(sv, k + 6 + hf, 64);
      float2 fa = __half22float2(((const __half2*)(xwp + (size_t)sa * 64))[cl]);
      float2 fb = __half22float2(((const __half2*)(xwp + (size_t)sb * 64))[cl]);
      float2 fc = __half22float2(((const __half2*)(xwp + (size_t)sc * 64))[cl]);
      float2 fd = __half22float2(((const __half2*)(xwp + (size_t)sd * 64))[cl]);
      a1.x += fa.x; a1.y += fa.y;
      a2.x += fb.x; a2.y += fb.y;
      a3.x += fc.x; a3.y += fc.y;
      a4.x += fd.x; a4.y += fd.y;
    }
    for (; k + 1 < m; k += 2) {
      unsigned sa = __shfl(sv, k + hf, 64);
      float2 fa = __half22float2(((const __half2*)(xwp + (size_t)sa * 64))[cl]);
      a1.x += fa.x; a1.y += fa.y;
    }
    if (k < m) {
      unsigned sa = __shfl(sv, k, 64);
      if (hf == 0) {
        float2 fa = __half22float2(((const __half2*)(xwp + (size_t)sa * 64))[cl]);
        a1.x += fa.x; a1.y += fa.y;
      }
    }
  }
  float2 acc;
  acc.x = (a1.x + a2.x) + (a3.x + a4.x);
  acc.y = (a1.y + a2.y) + (a3.y + a4.y);
  acc.x += __shfl(acc.x, lane ^ 32, 64);
  acc.y += __shfl(acc.y, lane ^ 32, 64);
  float dv = dinv[node];
  float vx = acc.x * dv, vy = acc.y * dv;

  if (hf != 0) return;

  const int c0 = 2 * cl;
  if (MODE == 0) {
    __half* out = (__half*)outv;
    __half2 o = __floats2half2_rn(fmaxf(vx + b0[c0], 0.0f), fmaxf(vy + b0[c0 + 1], 0.0f));
    ((__half2*)(out + (size_t)node * 64))[cl] = o;
  } else if (MODE == 2) {
    float* out = (float*)outv;
    float2 o;
    o.x = vx + b0[c0];
    o.y = vy + b0[c0 + 1];
    ((float2*)(out + (size_t)node * 64))[cl] = o;
  } else {
    float* out = (float*)outv;
    float bx = (c0 < 32) ? b0[c0] : b1[c0 - 32];
    float by = (c0 + 1 < 32) ? b0[c0 + 1] : b1[c0 + 1 - 32];
    vx += bx; vy += by;
    float ox = __shfl(vx, lane + 16, 64);
    float oy = __shfl(vy, lane + 16, 64);
    const int NZ = n * 32;
    if (cl < 16) {
      int j = node * 32 + c0;
      float n0 = jax_normal_at((unsigned)j);
      float n1 = jax_normal_at((unsigned)(j + 1));
      out[j]     = fmaf(n0, expf(0.5f * ox), vx);  // z
      out[j + 1] = fmaf(n1, expf(0.5f * oy), vy);
      out[NZ + j]     = vx;                        // mean
      out[NZ + j + 1] = vy;
    } else {
      int j = node * 32 + (c0 - 32);
      out[2 * NZ + j]     = vx;                    // logvar
      out[2 * NZ + j + 1] = vy;
    }
  }
}

// ---------------- launch ----------------

extern "C" void kernel_launch(void* const* d_in, const int* in_sizes, int n_in,
                              void* d_out, int out_size, void* d_ws, size_t ws_size,
                              hipStream_t stream) {
  const float* feat = (const float*)d_in[0];
  const float* cond = (const float*)d_in[1];
  const int*   eidx = (const int*)d_in[2];
  const float* W1  = (const float*)d_in[3];
  const float* b1  = (const float*)d_in[4];
  const float* Wm  = (const float*)d_in[5];
  const float* bm  = (const float*)d_in[6];
  const float* Wlv = (const float*)d_in[7];
  const float* blv = (const float*)d_in[8];
  const float* Wd  = (const float*)d_in[9];
  const float* bd  = (const float*)d_in[10];
  const float* Wo  = (const float*)d_in[11];
  const float* bo  = (const float*)d_in[12];

  const int n  = in_sizes[0] / 64;   // 50000 (< 65536 -> ssrc fits uint16)
  const int ne = in_sizes[2] / 2;    // 800000
  const int* srcI = eidx;
  const int* dstI = eidx + ne;
  const int nbuck = (n + 255) >> 8;  // 196

  // workspace carve-up (cntQ 16B-aligned for int4 loads)
  int*   cntQ   = (int*)d_ws;                     // n*4
  int*   rowptr = cntQ + (size_t)n * NQ;          // n+1
  int*   bh     = rowptr + n + 1;                 // 256
  int*   bcur   = bh + 256;                       // 256
  float* dinv   = (float*)(bcur + 256 + 3);       // n
  __half* xwp   = (__half*)(dinv + n);            // n*64
  __half* h     = xwp + (size_t)n * 64;           // n*64
  unsigned short* ssrc = (unsigned short*)(h + (size_t)n * 64); // ne
  unsigned* coarse = (unsigned*)(ssrc + ne + (ne & 1));         // ne

  float* dout   = (float*)d_out;
  float* zbuf   = dout;                        // n*32
  float* outbuf = dout + (size_t)3 * n * 32;   // n*64

  const int BT = 256;
  auto blk = [](long long t) { return (int)((t + 255) / 256); };
  const int nb_e  = blk(ne);
  const int nb_gw = blk((long long)n * 64);
  const int nb_g  = (n + 127) / 128;
  const int nb_fa = (ne + EPB - 1) / EPB;

  // ---- CSR setup ----
  hipMemsetAsync(cntQ, 0, (size_t)n * NQ * sizeof(int), stream);
  hipLaunchKernelGGL(degree_i_kernel, dim3(nb_e), dim3(BT), 0, stream, srcI, dstI, cntQ, ne);
  hipLaunchKernelGGL(bsum_kernel, dim3(nbuck), dim3(BT), 0, stream, cntQ, bh, n);
  hipLaunchKernelGGL(scanN_kernel, dim3(nbuck), dim3(BT), 0, stream,
                     cntQ, bh, rowptr, dinv, bcur, n, ne, nbuck);
  hipLaunchKernelGGL(fillA_kernel, dim3(nb_fa), dim3(BT), 0, stream, srcI, dstI, bcur, coarse, ne);
  hipLaunchKernelGGL(fillB_kernel, dim3(nbuck), dim3(BT), 0, stream, coarse, rowptr, cntQ, ssrc, n, ne);

  // ---- encoder conv1: h = relu(gcn(concat(feat,cond), W1, b1)) ----
  hipLaunchKernelGGL((gemm_mfma_kernel<64, 32, false, false>), dim3(nb_g), dim3(BT), 0, stream,
                     feat, cond, W1, nullptr, dinv, xwp, n);
  hipLaunchKernelGGL((gather_kernel<0>), dim3(nb_gw), dim3(BT), 0, stream,
                     rowptr, ssrc, xwp, dinv, b1, nullptr, h, n);

  // ---- mean/logvar packed conv + reparam z ----
  hipLaunchKernelGGL((gemm_mfma_kernel<64, 0, true, true>), dim3(nb_g), dim3(BT), 0, stream,
                     h, nullptr, Wm, Wlv, dinv, xwp, n);
  hipLaunchKernelGGL((gather_kernel<1>), dim3(nb_gw), dim3(BT), 0, stream,
                     rowptr, ssrc, xwp, dinv, bm, blv, dout, n);

  // ---- decoder conv1: hd = relu(gcn(concat(z,cond), Wd, bd)) ----
  hipLaunchKernelGGL((gemm_mfma_kernel<32, 32, false, false>), dim3(nb_g), dim3(BT), 0, stream,
                     zbuf, cond, Wd, nullptr, dinv, xwp, n);
  hipLaunchKernelGGL((gather_kernel<0>), dim3(nb_gw), dim3(BT), 0, stream,
                     rowptr, ssrc, xwp, dinv, bd, nullptr, h, n);

  // ---- decoder out conv ----
  hipLaunchKernelGGL((gemm_mfma_kernel<64, 0, true, false>), dim3(nb_g), dim3(BT), 0, stream,
                     h, nullptr, Wo, nullptr, dinv, xwp, n);
  hipLaunchKernelGGL((gather_kernel<2>), dim3(nb_gw), dim3(BT), 0, stream,
                     rowptr, ssrc, xwp, dinv, bo, nullptr, outbuf, n);
}